// Round 1
// baseline (59.561 us; speedup 1.0000x reference)
//
#include <hip/hip_runtime.h>
#include <hip/hip_bf16.h>

namespace {

constexpr int Bsz = 64, Cch = 3, Himg = 224, Wimg = 224, Ppat = 16;
constexpr int Dm = 768, NPW = 14, NPATCH = 196, SEQn = 197;
constexpr int Mtot = Bsz * NPATCH;   // 12544
constexpr int Ktot = 768, Ntot = 768;
constexpr int BM = 128, BN = 128, BK = 64;
constexpr int LDA = BK + 8;          // 72 bf16 -> 144B row stride (16B multiple)
constexpr int MT = Mtot / BM;        // 98
constexpr int NT = Ntot / BN;        // 6
constexpr int KT = Ktot / BK;        // 12
constexpr int TILE_ELEMS = BN * BK;  // 8192 bf16 = 16 KB per (bn,kt) tile

typedef __attribute__((ext_vector_type(8))) short bf16x8;
typedef __attribute__((ext_vector_type(4))) float f32x4;

__device__ inline unsigned short f2bf(float f) {
  __bf16 h = (__bf16)f;  // RNE; clang fuses pairs into v_cvt_pk_bf16_f32
  union { __bf16 h; unsigned short u; } c;
  c.h = h;
  return c.u;
}

// ---------------- W prepass: fp32 [K][N] -> bf16 swizzled tile images -------
// Output layout: tile (nb, kt), element (n', k') at flat index
//   (nb*KT + kt)*TILE_ELEMS + ((n'*BK + k') ^ ((n'&7) << 3))
// so that a linear global_load_lds stage yields the XOR-swizzled LDS image.
__global__ void wprep_kernel(const float* __restrict__ W,
                             unsigned short* __restrict__ Wt) {
  int cid = blockIdx.x * 256 + threadIdx.x;  // 0 .. 96*768-1
  int kc = cid / Ntot;                       // k-chunk of 8 (0..95)
  int n = cid - kc * Ntot;                   // 0..767
  int nb = n >> 7;
  int np = n & 127;
  int kt = kc >> 3;
  int k8 = (kc & 7) * 8;
  unsigned short tmp[8];
#pragma unroll
  for (int j = 0; j < 8; ++j) tmp[j] = f2bf(W[(kc * 8 + j) * Ntot + n]);
  int idx = np * BK + k8;
  int sidx = idx ^ ((np & 7) << 3);  // element-index XOR == byte bits 4..6
  unsigned short* dst = Wt + (nb * KT + kt) * TILE_ELEMS + sidx;
  *reinterpret_cast<ushort4*>(dst + 0) = make_ushort4(tmp[0], tmp[1], tmp[2], tmp[3]);
  *reinterpret_cast<ushort4*>(dst + 4) = make_ushort4(tmp[4], tmp[5], tmp[6], tmp[7]);
}

// ---------------- main GEMM: patches(bf16) x Wt(bf16) + bias + pos ----------
__global__ __launch_bounds__(256, 2)
void gemm_kernel(const float* __restrict__ x, const unsigned short* __restrict__ Wt,
                 const float* __restrict__ bias, const float* __restrict__ pos,
                 float* __restrict__ out) {
  __shared__ unsigned short As[BM][LDA];
  __shared__ unsigned short Bs[TILE_ELEMS];

  const int bm = blockIdx.x;
  const int bn = blockIdx.y;
  const int t = threadIdx.x;
  const int lane = t & 63;
  const int wid = t >> 6;
  const int wr = wid >> 1, wc = wid & 1;
  const int fr = lane & 15, fq = lane >> 4;

  // A staging geometry: thread covers float4 col a_cg (k = 4*a_cg), rows a_r0+16i
  const int a_cg = t & 15;
  const int a_r0 = t >> 4;
  int a_base[8];
#pragma unroll
  for (int i = 0; i < 8; ++i) {
    int m = bm * BM + a_r0 + 16 * i;
    int b = m / NPATCH;
    int pidx = m - b * NPATCH;
    int ph = pidx / NPW;
    int pw = pidx - ph * NPW;
    a_base[i] = ((b * Cch) * Himg + ph * Ppat) * Wimg + pw * Ppat;
  }

  const unsigned short* wt_base = Wt + bn * (KT * TILE_ELEMS);

  f32x4 acc[4][4];
#pragma unroll
  for (int mi = 0; mi < 4; ++mi)
#pragma unroll
    for (int ni = 0; ni < 4; ++ni) acc[mi][ni] = {0.f, 0.f, 0.f, 0.f};

  for (int kt = 0; kt < KT; ++kt) {
    // ---- B tile: async global->LDS, 4 x 16B per thread, linear (pre-swizzled src)
    {
      const unsigned short* src = wt_base + kt * TILE_ELEMS + t * 8;
#pragma unroll
      for (int i = 0; i < 4; ++i) {
        __builtin_amdgcn_global_load_lds(
            (const __attribute__((address_space(1))) unsigned int*)(src + i * 2048),
            (__attribute__((address_space(3))) unsigned int*)(&Bs[t * 8 + i * 2048]),
            16, 0, 0);
      }
    }
    // ---- A tile: gather fp32, convert, ds_write (overlaps the async B loads)
    {
      int kg = kt * BK + a_cg * 4;
      int c = kg >> 8;
      int pi = (kg >> 4) & 15;
      int pj = kg & 15;
      int off = (c * Himg + pi) * Wimg + pj;
#pragma unroll
      for (int i = 0; i < 8; ++i) {
        const float4 v = *reinterpret_cast<const float4*>(x + a_base[i] + off);
        ushort4 pk = make_ushort4(f2bf(v.x), f2bf(v.y), f2bf(v.z), f2bf(v.w));
        *reinterpret_cast<ushort4*>(&As[a_r0 + 16 * i][a_cg * 4]) = pk;
      }
    }
    __syncthreads();
#pragma unroll
    for (int ks = 0; ks < 2; ++ks) {
      bf16x8 af[4], bfr[4];
#pragma unroll
      for (int mi = 0; mi < 4; ++mi)
        af[mi] = *reinterpret_cast<const bf16x8*>(
            &As[wr * 64 + mi * 16 + fr][ks * 32 + fq * 8]);
#pragma unroll
      for (int ni = 0; ni < 4; ++ni) {
        int row = wc * 64 + ni * 16 + fr;
        int idx = (row * BK + ks * 32 + fq * 8) ^ ((row & 7) << 3);
        bfr[ni] = *reinterpret_cast<const bf16x8*>(&Bs[idx]);
      }
#pragma unroll
      for (int mi = 0; mi < 4; ++mi)
#pragma unroll
        for (int ni = 0; ni < 4; ++ni)
          acc[mi][ni] = __builtin_amdgcn_mfma_f32_16x16x32_bf16(
              af[mi], bfr[ni], acc[mi][ni], 0, 0, 0);
    }
    __syncthreads();
  }

  // ---- epilogue: + bias + pos_table, scatter to (b, 1+patch, d)
  const int n0w = bn * BN + wc * 64;
  float bv[4];
#pragma unroll
  for (int ni = 0; ni < 4; ++ni) bv[ni] = bias[n0w + ni * 16 + fr];
#pragma unroll
  for (int mi = 0; mi < 4; ++mi) {
#pragma unroll
    for (int j = 0; j < 4; ++j) {
      int m = bm * BM + wr * 64 + mi * 16 + fq * 4 + j;
      int b = m / NPATCH;
      int s = m - b * NPATCH + 1;  // +1: class token at s=0
      float* orow = out + (b * SEQn + s) * Dm + n0w;
      const float* prow = pos + s * Dm + n0w;
#pragma unroll
      for (int ni = 0; ni < 4; ++ni) {
        int d = ni * 16 + fr;
        orow[d] = acc[mi][ni][j] + bv[ni] + prow[d];
      }
    }
  }
}

// ---------------- class-token row ------------------------------------------
__global__ void cls_kernel(const float* __restrict__ pos, const float* __restrict__ cls,
                           float* __restrict__ out) {
  int i = blockIdx.x * 256 + threadIdx.x;  // 0..64*768-1
  int b = i / Dm;
  int d = i - b * Dm;
  out[b * (SEQn * Dm) + d] = cls[d] + pos[d];
}

}  // namespace

extern "C" void kernel_launch(void* const* d_in, const int* in_sizes, int n_in,
                              void* d_out, int out_size, void* d_ws, size_t ws_size,
                              hipStream_t stream) {
  const float* x = (const float*)d_in[0];
  const float* W = (const float*)d_in[1];
  const float* bias = (const float*)d_in[2];
  const float* pos = (const float*)d_in[3];
  const float* cls = (const float*)d_in[4];
  float* out = (float*)d_out;
  unsigned short* Wt = (unsigned short*)d_ws;  // needs 768*768*2 = 1.18 MB

  wprep_kernel<<<(Ktot / 8) * Ntot / 256, 256, 0, stream>>>(W, Wt);
  dim3 grid(MT, NT);
  gemm_kernel<<<grid, 256, 0, stream>>>(x, Wt, bias, pos, out);
  cls_kernel<<<Bsz * Dm / 256, 256, 0, stream>>>(pos, cls, out);
}

// Round 2
// 48.477 us; speedup vs baseline: 1.2286x; 1.2286x over previous
//
#include <hip/hip_runtime.h>
#include <hip/hip_bf16.h>

namespace {

constexpr int Bsz = 64, Cch = 3, Himg = 224, Wimg = 224, Ppat = 16;
constexpr int Dm = 768, NPW = 14, NPATCH = 196, SEQn = 197;
constexpr int Mtot = Bsz * NPATCH;   // 12544
constexpr int Ktot = 768, Ntot = 768;
constexpr int BM = 64, BN = 128, BK = 64;
constexpr int MT = Mtot / BM;        // 196
constexpr int NT = Ntot / BN;        // 6
constexpr int KT = Ktot / BK;        // 12
constexpr int NBLK = MT * NT;        // 1176 (divisible by 8 -> clean XCD chunks)
constexpr int TILE_A = BM * BK;      // 4096 bf16 = 8 KB
constexpr int TILE_B = BN * BK;      // 8192 bf16 = 16 KB

typedef __attribute__((ext_vector_type(8))) short bf16x8;
typedef __attribute__((ext_vector_type(4))) float f32x4;

__device__ inline unsigned short f2bf(float f) {
  __bf16 h = (__bf16)f;  // RNE; clang fuses pairs into v_cvt_pk_bf16_f32
  union { __bf16 h; unsigned short u; } c;
  c.h = h;
  return c.u;
}

// ---------------- prepass: W fp32 [K][N] -> bf16 swizzled tiles, + cls row --
// W tile image: tile (nb, kt), element (n', k') at flat index
//   (nb*KT + kt)*TILE_B + ((n'*BK + k') ^ ((n'&7) << 3))
// so a LINEAR global_load_lds stage yields the XOR-swizzled LDS image (m173).
__global__ void prep_kernel(const float* __restrict__ W, unsigned short* __restrict__ Wt,
                            const float* __restrict__ pos, const float* __restrict__ cls,
                            float* __restrict__ out) {
  int bid = blockIdx.x;
  if (bid < (Ktot / 8) * Ntot / 256) {  // 288 blocks: W prep
    int cid = bid * 256 + threadIdx.x;
    int kc = cid / Ntot;                // k-chunk of 8 (0..95)
    int n = cid - kc * Ntot;
    int nb = n >> 7;
    int np = n & 127;
    int kt = kc >> 3;
    int k8 = (kc & 7) * 8;
    unsigned short tmp[8];
#pragma unroll
    for (int j = 0; j < 8; ++j) tmp[j] = f2bf(W[(kc * 8 + j) * Ntot + n]);
    int idx = np * BK + k8;
    int sidx = idx ^ ((np & 7) << 3);
    unsigned short* dst = Wt + (nb * KT + kt) * TILE_B + sidx;
    *reinterpret_cast<ushort4*>(dst + 0) = make_ushort4(tmp[0], tmp[1], tmp[2], tmp[3]);
    *reinterpret_cast<ushort4*>(dst + 4) = make_ushort4(tmp[4], tmp[5], tmp[6], tmp[7]);
  } else {  // 192 blocks: class-token row (s = 0)
    int i = (bid - (Ktot / 8) * Ntot / 256) * 256 + threadIdx.x;  // 0..64*768-1
    int b = i / Dm;
    int d = i - b * Dm;
    out[b * (SEQn * Dm) + d] = cls[d] + pos[d];
  }
}

// ---------------- main GEMM: 64x128 tile, 8 waves, 2-phase dbuf pipeline ----
__global__ __launch_bounds__(512, 6)
void gemm_kernel(const float* __restrict__ x, const unsigned short* __restrict__ Wt,
                 const float* __restrict__ bias, const float* __restrict__ pos,
                 float* __restrict__ out) {
  __shared__ unsigned short As[2][TILE_A];
  __shared__ unsigned short Bs[2][TILE_B];

  // XCD-chunked bijective swizzle (NBLK % 8 == 0): each XCD gets a contiguous
  // chunk; within a chunk, bn varies fastest -> A-panel reused 6x in one L2.
  const int orig = blockIdx.x;
  const int wg = (orig & 7) * (NBLK / 8) + (orig >> 3);
  const int bm = wg / NT;
  const int bn = wg - bm * NT;

  const int t = threadIdx.x;
  const int lane = t & 63;
  const int wid = t >> 6;              // 8 waves: 2 (M) x 4 (N)
  const int wr = wid >> 2, wc = wid & 3;
  const int fr = lane & 15, fq = lane >> 4;

  // A staging geometry: thread covers float4 k-group c4, rows r0 and r0+32
  const int c4 = t & 15;
  const int r0 = t >> 4;
  int a_base[2];
#pragma unroll
  for (int i = 0; i < 2; ++i) {
    int m = bm * BM + r0 + 32 * i;
    int b = m / NPATCH;
    int pidx = m - b * NPATCH;
    int ph = pidx / NPW;
    int pw = pidx - ph * NPW;
    a_base[i] = ((b * Cch) * Himg + ph * Ppat) * Wimg + pw * Ppat;
  }
  const unsigned short* wt_base = Wt + bn * (KT * TILE_B);

  float4 av[2];
  auto LOADA = [&](int kt) {  // issue global loads early (latency hides under MFMA)
    int kg = kt * BK + c4 * 4;
    int c = kg >> 8;
    int pi = (kg >> 4) & 15;
    int pj = kg & 15;
    int off = (c * Himg + pi) * Wimg + pj;
#pragma unroll
    for (int i = 0; i < 2; ++i)
      av[i] = *reinterpret_cast<const float4*>(x + a_base[i] + off);
  };
  auto WRITEA = [&](int buf) {  // convert + swizzled ds_write (late)
#pragma unroll
    for (int i = 0; i < 2; ++i) {
      int row = r0 + 32 * i;
      int idx = (row * BK + c4 * 4) ^ ((row & 7) << 3);
      ushort4 pk = make_ushort4(f2bf(av[i].x), f2bf(av[i].y), f2bf(av[i].z), f2bf(av[i].w));
      *reinterpret_cast<ushort4*>(&As[buf][idx]) = pk;
    }
  };
  auto STAGEB = [&](int buf, int kt) {  // async, linear dest (pre-swizzled src)
    const unsigned short* src = wt_base + kt * TILE_B + t * 8;
#pragma unroll
    for (int i = 0; i < 2; ++i) {
      __builtin_amdgcn_global_load_lds(
          (const __attribute__((address_space(1))) unsigned int*)(src + i * 4096),
          (__attribute__((address_space(3))) unsigned int*)(&Bs[buf][t * 8 + i * 4096]),
          16, 0, 0);
    }
  };

  f32x4 acc[2][2];
#pragma unroll
  for (int mi = 0; mi < 2; ++mi)
#pragma unroll
    for (int ni = 0; ni < 2; ++ni) acc[mi][ni] = {0.f, 0.f, 0.f, 0.f};

  // prologue: stage tile 0
  LOADA(0);
  STAGEB(0, 0);
  WRITEA(0);
  __syncthreads();

  for (int kt = 0; kt < KT; ++kt) {
    const int cur = kt & 1, nxt = cur ^ 1;
    if (kt + 1 < KT) {
      LOADA(kt + 1);        // phase 1: issue next A loads (to regs)
      STAGEB(nxt, kt + 1);  // phase 2: issue next B loads (async to LDS)
    }
    // phase 3: compute current tile
#pragma unroll
    for (int ks = 0; ks < 2; ++ks) {
      bf16x8 af[2], bfr[2];
#pragma unroll
      for (int mi = 0; mi < 2; ++mi) {
        int row = wr * 32 + mi * 16 + fr;
        int idx = (row * BK + ks * 32 + fq * 8) ^ ((row & 7) << 3);
        af[mi] = *reinterpret_cast<const bf16x8*>(&As[cur][idx]);
      }
#pragma unroll
      for (int ni = 0; ni < 2; ++ni) {
        int n = wc * 32 + ni * 16 + fr;
        int idx = (n * BK + ks * 32 + fq * 8) ^ ((n & 7) << 3);
        bfr[ni] = *reinterpret_cast<const bf16x8*>(&Bs[cur][idx]);
      }
#pragma unroll
      for (int mi = 0; mi < 2; ++mi)
#pragma unroll
        for (int ni = 0; ni < 2; ++ni)
          acc[mi][ni] = __builtin_amdgcn_mfma_f32_16x16x32_bf16(
              af[mi], bfr[ni], acc[mi][ni], 0, 0, 0);
    }
    // phase 4: A regs arrived during compute -> convert + ds_write
    if (kt + 1 < KT) WRITEA(nxt);
    __syncthreads();  // drains vmcnt (gload_lds) + lgkm (ds_write)
  }

  // epilogue: + bias + pos_table, scatter to (b, 1+patch, d)
  const int n0 = bn * BN + wc * 32;
  float bv[2];
#pragma unroll
  for (int ni = 0; ni < 2; ++ni) bv[ni] = bias[n0 + ni * 16 + fr];
#pragma unroll
  for (int mi = 0; mi < 2; ++mi) {
#pragma unroll
    for (int j = 0; j < 4; ++j) {
      int m = bm * BM + wr * 32 + mi * 16 + fq * 4 + j;
      int b = m / NPATCH;
      int s = m - b * NPATCH + 1;  // +1: class token at s=0
      float* orow = out + (b * SEQn + s) * Dm + n0;
      const float* prow = pos + s * Dm + n0;
#pragma unroll
      for (int ni = 0; ni < 2; ++ni) {
        int d = ni * 16 + fr;
        orow[d] = acc[mi][ni][j] + bv[ni] + prow[d];
      }
    }
  }
}

}  // namespace

extern "C" void kernel_launch(void* const* d_in, const int* in_sizes, int n_in,
                              void* d_out, int out_size, void* d_ws, size_t ws_size,
                              hipStream_t stream) {
  const float* x = (const float*)d_in[0];
  const float* W = (const float*)d_in[1];
  const float* bias = (const float*)d_in[2];
  const float* pos = (const float*)d_in[3];
  const float* cls = (const float*)d_in[4];
  float* out = (float*)d_out;
  unsigned short* Wt = (unsigned short*)d_ws;  // 768*768*2 = 1.18 MB

  prep_kernel<<<(Ktot / 8) * Ntot / 256 + Bsz * Dm / 256, 256, 0, stream>>>(W, Wt, pos, cls, out);
  gemm_kernel<<<NBLK, 512, 0, stream>>>(x, Wt, bias, pos, out);
}